// Round 2
// baseline (585.206 us; speedup 1.0000x reference)
//
#include <hip/hip_runtime.h>
#include <hip/hip_bf16.h>
#include <math.h>

// Dims from the reference
#define HH    8
#define DKK   64
#define GD    512
#define SD    3072
#define HID_  512
#define BB    16384

typedef unsigned short ushort_t;
typedef __attribute__((ext_vector_type(8))) short bf16x8;
typedef __attribute__((ext_vector_type(4))) float f32x4;

__device__ __forceinline__ float bf2f(ushort_t u) {
  union { unsigned int i; float f; } c; c.i = ((unsigned int)u) << 16; return c.f;
}
__device__ __forceinline__ ushort_t f2bf(float f) {
  union { float f; unsigned int i; } c; c.f = f;
  unsigned int x = c.i;
  return (ushort_t)((x + 0x7FFFu + ((x >> 16) & 1u)) >> 16);  // RNE
}

__device__ __forceinline__ void async_cp16(const ushort_t* gsrc, ushort_t* ldst) {
  __builtin_amdgcn_global_load_lds(
      (const __attribute__((address_space(1))) unsigned int*)gsrc,
      (__attribute__((address_space(3))) unsigned int*)ldst, 16, 0, 0);
}

// ---------------------------------------------------------------------------
// C[m][n] = sum_k A[m][k] * Bt[n][k]  (+ bias[n]), bf16 in, bf16 out.
// BM=BN=128, BK=32. 256 threads = 4 waves, each wave owns a 64x64 subtile
// (4x4 grid of 16x16x32 MFMA). EPI: 0 = bias+store, 1 = gelu(bias+x)+store.
// ---------------------------------------------------------------------------
template <int EPI>
__global__ __launch_bounds__(256) void gemm_bt(
    const ushort_t* __restrict__ A, const ushort_t* __restrict__ Bt,
    ushort_t* __restrict__ C, const float* __restrict__ bias,
    int M, int N, int K) {
  __shared__ __align__(16) ushort_t As[128 * 32];
  __shared__ __align__(16) ushort_t Bs[128 * 32];
  const int tid = threadIdx.x;
  const int wv = tid >> 6;
  const int lane = tid & 63;
  const int m0 = blockIdx.y * 128;
  const int n0 = blockIdx.x * 128;
  const int srow = lane >> 2;        // 0..15 within a 16-row chunk
  const int scol = (lane & 3) * 8;   // 0,8,16,24
  const int wm = wv & 1, wn = wv >> 1;
  const int lr = lane & 15, quad = lane >> 4;

  f32x4 acc[4][4];
#pragma unroll
  for (int i = 0; i < 4; ++i)
#pragma unroll
    for (int j = 0; j < 4; ++j) acc[i][j] = (f32x4){0.f, 0.f, 0.f, 0.f};

  const ushort_t* Ab = A + (size_t)m0 * K;
  const ushort_t* Bb = Bt + (size_t)n0 * K;

  for (int k0 = 0; k0 < K; k0 += 32) {
    __syncthreads();
#pragma unroll
    for (int i = 0; i < 2; ++i) {
      const int chunk = i * 4 + wv;          // 0..7, wave-uniform
      const int row = chunk * 16 + srow;     // 0..127
      async_cp16(Ab + (size_t)row * K + (k0 + scol), As + chunk * 512);
      async_cp16(Bb + (size_t)row * K + (k0 + scol), Bs + chunk * 512);
    }
    __syncthreads();
    bf16x8 af[4], bfr[4];
#pragma unroll
    for (int i = 0; i < 4; ++i)
      af[i] = *(const bf16x8*)&As[(wm * 64 + i * 16 + lr) * 32 + quad * 8];
#pragma unroll
    for (int j = 0; j < 4; ++j)
      bfr[j] = *(const bf16x8*)&Bs[(wn * 64 + j * 16 + lr) * 32 + quad * 8];
#pragma unroll
    for (int i = 0; i < 4; ++i)
#pragma unroll
      for (int j = 0; j < 4; ++j)
        acc[i][j] = __builtin_amdgcn_mfma_f32_16x16x32_bf16(af[i], bfr[j], acc[i][j], 0, 0, 0);
  }

#pragma unroll
  for (int i = 0; i < 4; ++i) {
    const int mg = m0 + wm * 64 + i * 16 + quad * 4;
#pragma unroll
    for (int j = 0; j < 4; ++j) {
      const int ng = n0 + wn * 64 + j * 16 + lr;
      const float bvv = bias ? bias[ng] : 0.0f;
#pragma unroll
      for (int r = 0; r < 4; ++r) {
        float v = acc[i][j][r] + bvv;
        if (EPI == 1) v = 0.5f * v * (1.0f + erff(v * 0.70710678118654752440f));
        C[(size_t)(mg + r) * N + ng] = f2bf(v);
      }
    }
  }
}

// fp32 -> bf16 bulk convert, 8 elements/thread, exact-division sizes only.
__global__ __launch_bounds__(256) void cvt_f32_bf16(const float* __restrict__ src,
                                                    ushort_t* __restrict__ dst) {
  const size_t i8 = ((size_t)blockIdx.x * 256 + threadIdx.x) * 8;
  float4 a = *(const float4*)(src + i8);
  float4 b = *(const float4*)(src + i8 + 4);
  ushort_t o[8];
  o[0] = f2bf(a.x); o[1] = f2bf(a.y); o[2] = f2bf(a.z); o[3] = f2bf(a.w);
  o[4] = f2bf(b.x); o[5] = f2bf(b.y); o[6] = f2bf(b.z); o[7] = f2bf(b.w);
  *(uint4*)(dst + i8) = *(const uint4*)o;
}

// Wvp[s][c] = Wv[h=c>>6][s][d=c&63], fp32 -> bf16. 8 outputs/thread (same h).
__global__ __launch_bounds__(256) void permute_wv(const float* __restrict__ Wv,
                                                  ushort_t* __restrict__ Wvp) {
  const int idx = (blockIdx.x * 256 + threadIdx.x) * 8;
  const int s = idx >> 9;
  const int c = idx & 511;
  const float* src = Wv + (size_t)(c >> 6) * (SD * DKK) + (size_t)s * DKK + (c & 63);
  float4 a = *(const float4*)src;
  float4 b = *(const float4*)(src + 4);
  ushort_t o[8];
  o[0] = f2bf(a.x); o[1] = f2bf(a.y); o[2] = f2bf(a.z); o[3] = f2bf(a.w);
  o[4] = f2bf(b.x); o[5] = f2bf(b.y); o[6] = f2bf(b.z); o[7] = f2bf(b.w);
  *(uint4*)(Wvp + idx) = *(const uint4*)o;
}

// dst[C][R] = src[R][C]^T, fp32 in -> bf16 out, 32x32 LDS tiles, block (32,8)
__global__ __launch_bounds__(256) void transpose_k(const float* __restrict__ src,
                                                   ushort_t* __restrict__ dst,
                                                   int R, int C) {
  __shared__ ushort_t tile[32][33];
  const int bx = blockIdx.x * 32;  // col base in src
  const int by = blockIdx.y * 32;  // row base in src
  const int tx = threadIdx.x, ty = threadIdx.y;
#pragma unroll
  for (int i = 0; i < 32; i += 8)
    tile[ty + i][tx] = f2bf(src[(size_t)(by + ty + i) * C + (bx + tx)]);
  __syncthreads();
#pragma unroll
  for (int i = 0; i < 32; i += 8)
    dst[(size_t)(bx + ty + i) * R + (by + tx)] = tile[tx][ty + i];
}

// c0[j] = sum_c bv[c]*Wo[c][j] + bo[j]   (all fp32)
__global__ __launch_bounds__(256) void c0_kernel(const float* __restrict__ bv,
                                                 const float* __restrict__ Wo,
                                                 const float* __restrict__ bo,
                                                 float* __restrict__ c0) {
  const int j = blockIdx.x * 256 + threadIdx.x;
  float s = bo[j];
  for (int c = 0; c < 512; ++c) s += bv[c] * Wo[c * 512 + j];
  c0[j] = s;
}

// out = LN(t + res) * g + b over rows of 512; one wave per row.
// t is bf16; res fp32 or bf16; out fp32 or bf16; g,b fp32.
template <int RES_F32, int OUT_F32>
__global__ __launch_bounds__(256) void ln_kernel(const ushort_t* __restrict__ t,
                                                 const void* __restrict__ res_,
                                                 const float* __restrict__ g,
                                                 const float* __restrict__ b,
                                                 void* __restrict__ out_) {
  const int row = blockIdx.x * 4 + (threadIdx.x >> 6);
  const int lane = threadIdx.x & 63;
  const size_t base = (size_t)row * 512 + lane * 8;
  uint4 tv = *(const uint4*)(t + base);
  const ushort_t* tp = (const ushort_t*)&tv;
  float r[8];
  if (RES_F32) {
    const float* res = (const float*)res_;
    float4 a = *(const float4*)(res + base);
    float4 c = *(const float4*)(res + base + 4);
    r[0] = a.x; r[1] = a.y; r[2] = a.z; r[3] = a.w;
    r[4] = c.x; r[5] = c.y; r[6] = c.z; r[7] = c.w;
  } else {
    const ushort_t* res = (const ushort_t*)res_;
    uint4 rv = *(const uint4*)(res + base);
    const ushort_t* rp = (const ushort_t*)&rv;
#pragma unroll
    for (int k = 0; k < 8; ++k) r[k] = bf2f(rp[k]);
  }
  float x[8];
  float s = 0.f, sq = 0.f;
#pragma unroll
  for (int k = 0; k < 8; ++k) {
    float v = bf2f(tp[k]) + r[k];
    x[k] = v; s += v; sq += v * v;
  }
#pragma unroll
  for (int off = 32; off > 0; off >>= 1) {
    s += __shfl_xor(s, off);
    sq += __shfl_xor(sq, off);
  }
  const float mean = s * (1.0f / 512.0f);
  const float var = sq * (1.0f / 512.0f) - mean * mean;
  const float rstd = rsqrtf(var + 1e-5f);
  float4 gv0 = *(const float4*)(g + lane * 8);
  float4 gv1 = *(const float4*)(g + lane * 8 + 4);
  float4 bv0 = *(const float4*)(b + lane * 8);
  float4 bv1 = *(const float4*)(b + lane * 8 + 4);
  const float gg[8] = {gv0.x, gv0.y, gv0.z, gv0.w, gv1.x, gv1.y, gv1.z, gv1.w};
  const float bb[8] = {bv0.x, bv0.y, bv0.z, bv0.w, bv1.x, bv1.y, bv1.z, bv1.w};
  float y[8];
#pragma unroll
  for (int k = 0; k < 8; ++k) y[k] = (x[k] - mean) * rstd * gg[k] + bb[k];
  if (OUT_F32) {
    float* out = (float*)out_;
    *(float4*)(out + base) = make_float4(y[0], y[1], y[2], y[3]);
    *(float4*)(out + base + 4) = make_float4(y[4], y[5], y[6], y[7]);
  } else {
    ushort_t* out = (ushort_t*)out_;
    uint4 ov; ushort_t* op = (ushort_t*)&ov;
#pragma unroll
    for (int k = 0; k < 8; ++k) op[k] = f2bf(y[k]);
    *(uint4*)(out + base) = ov;
  }
}

extern "C" void kernel_launch(void* const* d_in, const int* in_sizes, int n_in,
                              void* d_out, int out_size, void* d_ws, size_t ws_size,
                              hipStream_t stream) {
  const float* h_g  = (const float*)d_in[0];
  const float* h_s  = (const float*)d_in[1];
  // d_in[2..5] = Wq,bq,Wk,bk — dead code (softmax over 1 key == 1, attn == V)
  const float* Wv   = (const float*)d_in[6];
  const float* bv   = (const float*)d_in[7];
  const float* Wo   = (const float*)d_in[8];
  const float* bo   = (const float*)d_in[9];
  const float* ln1g = (const float*)d_in[10];
  const float* ln1b = (const float*)d_in[11];
  const float* W1   = (const float*)d_in[12];
  const float* b1   = (const float*)d_in[13];
  const float* W2   = (const float*)d_in[14];
  const float* b2   = (const float*)d_in[15];
  const float* ln2g = (const float*)d_in[16];
  const float* ln2b = (const float*)d_in[17];

  char* ws = (char*)d_ws;
  ushort_t* WoT = (ushort_t*)(ws + 0);           // 512x512 bf16   (0.5 MB)
  ushort_t* W1T = (ushort_t*)(ws + 524288);      // 1024x512 bf16  (1 MB)
  ushort_t* W2T = (ushort_t*)(ws + 1572864);     // 512x1024 bf16  (1 MB)
  ushort_t* Wvp = (ushort_t*)(ws + 2621440);     // 3072x512 bf16  (3 MB)
  ushort_t* WcT = (ushort_t*)(ws + 5767168);     // 512x3072 bf16  (3 MB)
  float*    c0f = (float*)(ws + 8912896);        // 512 f32
  ushort_t* hsb = (ushort_t*)(ws + 9437184);     // 16384x3072 bf16 (96 MiB)
  ushort_t* u   = hsb;                           // 16384x1024 bf16 — reuses hsb (dead)
  ushort_t* t1  = (ushort_t*)(ws + 110100480);   // 16384x512 bf16 (16 MiB)
  ushort_t* t2  = t1;                            // reuses t1 (dead after LN1)
  ushort_t* x   = (ushort_t*)(ws + 126877696);   // 16384x512 bf16 (16 MiB)
  (void)in_sizes; (void)n_in; (void)out_size; (void)ws_size;

  // --- prep ---
  hipLaunchKernelGGL(cvt_f32_bf16, dim3(24576), dim3(256), 0, stream, h_s, hsb);
  hipLaunchKernelGGL(permute_wv, dim3(768), dim3(256), 0, stream, Wv, Wvp);
  hipLaunchKernelGGL(transpose_k, dim3(16, 16), dim3(32, 8), 0, stream, Wo, WoT, 512, 512);
  hipLaunchKernelGGL(transpose_k, dim3(32, 16), dim3(32, 8), 0, stream, W1, W1T, 512, 1024);
  hipLaunchKernelGGL(transpose_k, dim3(16, 32), dim3(32, 8), 0, stream, W2, W2T, 1024, 512);
  hipLaunchKernelGGL(c0_kernel, dim3(2), dim3(256), 0, stream, bv, Wo, bo, c0f);

  // --- folded weight: WcT[j][s] = sum_c WoT[j][c] * Wvp[s][c]  (M=512,N=3072,K=512)
  hipLaunchKernelGGL(gemm_bt<0>, dim3(24, 4), dim3(256), 0, stream,
                     WoT, Wvp, WcT, (const float*)nullptr, 512, 3072, 512);
  // --- t1 = h_s @ Wc + c0   (M=16384,N=512,K=3072)
  hipLaunchKernelGGL(gemm_bt<0>, dim3(4, 128), dim3(256), 0, stream,
                     hsb, WcT, t1, c0f, BB, 512, 3072);
  // --- x = LN1(t1 + h_g)   (res fp32, out bf16)
  hipLaunchKernelGGL((ln_kernel<1, 0>), dim3(4096), dim3(256), 0, stream,
                     t1, (const void*)h_g, ln1g, ln1b, (void*)x);
  // --- u = gelu(x @ W1 + b1)   (M=16384,N=1024,K=512)
  hipLaunchKernelGGL(gemm_bt<1>, dim3(8, 128), dim3(256), 0, stream,
                     x, W1T, u, b1, BB, 1024, 512);
  // --- t2 = u @ W2 + b2   (M=16384,N=512,K=1024)
  hipLaunchKernelGGL(gemm_bt<0>, dim3(4, 128), dim3(256), 0, stream,
                     u, W2T, t2, b2, BB, 512, 1024);
  // --- out = LN2(t2 + x)   (res bf16, out fp32)
  hipLaunchKernelGGL((ln_kernel<0, 1>), dim3(4096), dim3(256), 0, stream,
                     t2, (const void*)x, ln2g, ln2b, d_out);
}

// Round 3
// 574.234 us; speedup vs baseline: 1.0191x; 1.0191x over previous
//
#include <hip/hip_runtime.h>
#include <hip/hip_bf16.h>
#include <math.h>

// Dims from the reference
#define HH    8
#define DKK   64
#define GD    512
#define SD    3072
#define HID_  512
#define BB    16384

typedef unsigned short ushort_t;
typedef __attribute__((ext_vector_type(8))) short bf16x8;
typedef __attribute__((ext_vector_type(4))) float f32x4;

__device__ __forceinline__ float bf2f(ushort_t u) {
  union { unsigned int i; float f; } c; c.i = ((unsigned int)u) << 16; return c.f;
}
__device__ __forceinline__ ushort_t f2bf(float f) {
  union { float f; unsigned int i; } c; c.f = f;
  unsigned int x = c.i;
  return (ushort_t)((x + 0x7FFFu + ((x >> 16) & 1u)) >> 16);  // RNE
}
__device__ __forceinline__ unsigned int pk_bf16(float a, float b) {
  __hip_bfloat162 h = __float22bfloat162_rn(make_float2(a, b));
  union { __hip_bfloat162 h; unsigned int u; } c; c.h = h; return c.u;
}

__device__ __forceinline__ void async_cp16(const ushort_t* gsrc, ushort_t* ldst) {
  __builtin_amdgcn_global_load_lds(
      (const __attribute__((address_space(1))) unsigned int*)gsrc,
      (__attribute__((address_space(3))) unsigned int*)ldst, 16, 0, 0);
}

// tanh-form GELU: max |delta| vs exact erf-GELU ~3e-3, far under tolerance.
__device__ __forceinline__ float gelu_tanh(float x) {
  float y = 0.79788456080286535588f * (x + 0.044715f * x * x * x);
  float e = __expf(2.0f * y);            // inf -> th=1, 0 -> th=-1 (graceful)
  float th = 1.0f - 2.0f / (e + 1.0f);
  return 0.5f * x * (1.0f + th);
}

// ---------------------------------------------------------------------------
// C[m][n] = sum_k A[m][k] * Bt[n][k]  (+ bias[n]), bf16 in, bf16 out.
// BM=BN=128, BK=32. 256 threads = 4 waves, each wave owns a 64x64 subtile
// (4x4 grid of 16x16x32 MFMA). EPI: 0 = bias+store, 1 = gelu(bias+x)+store.
// ---------------------------------------------------------------------------
template <int EPI>
__global__ __launch_bounds__(256) void gemm_bt(
    const ushort_t* __restrict__ A, const ushort_t* __restrict__ Bt,
    ushort_t* __restrict__ C, const float* __restrict__ bias,
    int M, int N, int K) {
  __shared__ __align__(16) ushort_t As[128 * 32];
  __shared__ __align__(16) ushort_t Bs[128 * 32];
  const int tid = threadIdx.x;
  const int wv = tid >> 6;
  const int lane = tid & 63;
  const int m0 = blockIdx.y * 128;
  const int n0 = blockIdx.x * 128;
  const int srow = lane >> 2;        // 0..15 within a 16-row chunk
  const int scol = (lane & 3) * 8;   // 0,8,16,24
  const int wm = wv & 1, wn = wv >> 1;
  const int lr = lane & 15, quad = lane >> 4;

  f32x4 acc[4][4];
#pragma unroll
  for (int i = 0; i < 4; ++i)
#pragma unroll
    for (int j = 0; j < 4; ++j) acc[i][j] = (f32x4){0.f, 0.f, 0.f, 0.f};

  const ushort_t* Ab = A + (size_t)m0 * K;
  const ushort_t* Bb = Bt + (size_t)n0 * K;

  for (int k0 = 0; k0 < K; k0 += 32) {
    __syncthreads();
#pragma unroll
    for (int i = 0; i < 2; ++i) {
      const int chunk = i * 4 + wv;          // 0..7, wave-uniform
      const int row = chunk * 16 + srow;     // 0..127
      async_cp16(Ab + (size_t)row * K + (k0 + scol), As + chunk * 512);
      async_cp16(Bb + (size_t)row * K + (k0 + scol), Bs + chunk * 512);
    }
    __syncthreads();
    bf16x8 af[4], bfr[4];
#pragma unroll
    for (int i = 0; i < 4; ++i)
      af[i] = *(const bf16x8*)&As[(wm * 64 + i * 16 + lr) * 32 + quad * 8];
#pragma unroll
    for (int j = 0; j < 4; ++j)
      bfr[j] = *(const bf16x8*)&Bs[(wn * 64 + j * 16 + lr) * 32 + quad * 8];
#pragma unroll
    for (int i = 0; i < 4; ++i)
#pragma unroll
      for (int j = 0; j < 4; ++j)
        acc[i][j] = __builtin_amdgcn_mfma_f32_16x16x32_bf16(af[i], bfr[j], acc[i][j], 0, 0, 0);
  }

#pragma unroll
  for (int i = 0; i < 4; ++i) {
    const int mg = m0 + wm * 64 + i * 16 + quad * 4;
#pragma unroll
    for (int j = 0; j < 4; ++j) {
      const int ng = n0 + wn * 64 + j * 16 + lr;
      const float bvv = bias ? bias[ng] : 0.0f;
#pragma unroll
      for (int r = 0; r < 4; ++r) {
        float v = acc[i][j][r] + bvv;
        if (EPI == 1) v = gelu_tanh(v);
        C[(size_t)(mg + r) * N + ng] = f2bf(v);
      }
    }
  }
}

// ---------------------------------------------------------------------------
// Same GEMM, but A is fp32 in HBM: staged via regs (float4 x4 -> cvt_pk ->
// ds_write_b128 x2). B stays bf16 via global_load_lds. Kills the separate
// fp32->bf16 conversion pass over h_s (300 MB of traffic).
// ---------------------------------------------------------------------------
__global__ __launch_bounds__(256) void gemm_bt_f32a(
    const float* __restrict__ A, const ushort_t* __restrict__ Bt,
    ushort_t* __restrict__ C, const float* __restrict__ bias,
    int M, int N, int K) {
  __shared__ __align__(16) ushort_t As[128 * 32];
  __shared__ __align__(16) ushort_t Bs[128 * 32];
  const int tid = threadIdx.x;
  const int wv = tid >> 6;
  const int lane = tid & 63;
  const int m0 = blockIdx.y * 128;
  const int n0 = blockIdx.x * 128;
  const int srow = lane >> 2;
  const int scol = (lane & 3) * 8;
  const int wm = wv & 1, wn = wv >> 1;
  const int lr = lane & 15, quad = lane >> 4;
  // A staging: thread covers row=tid>>1 (0..127), 16 consecutive k at (tid&1)*16
  const int arow = tid >> 1;
  const int ach = (tid & 1) * 16;

  f32x4 acc[4][4];
#pragma unroll
  for (int i = 0; i < 4; ++i)
#pragma unroll
    for (int j = 0; j < 4; ++j) acc[i][j] = (f32x4){0.f, 0.f, 0.f, 0.f};

  const float* Ag = A + (size_t)(m0 + arow) * K + ach;
  const ushort_t* Bb = Bt + (size_t)n0 * K;

  for (int k0 = 0; k0 < K; k0 += 32) {
    __syncthreads();
    // A: fp32 loads to regs (64 B/thread)
    float4 f0 = *(const float4*)(Ag + k0);
    float4 f1 = *(const float4*)(Ag + k0 + 4);
    float4 f2 = *(const float4*)(Ag + k0 + 8);
    float4 f3 = *(const float4*)(Ag + k0 + 12);
    // B: async direct-to-LDS
#pragma unroll
    for (int i = 0; i < 2; ++i) {
      const int chunk = i * 4 + wv;
      const int row = chunk * 16 + srow;
      async_cp16(Bb + (size_t)row * K + (k0 + scol), Bs + chunk * 512);
    }
    // cvt + LDS write (32 B/thread)
    unsigned int p[8];
    p[0] = pk_bf16(f0.x, f0.y); p[1] = pk_bf16(f0.z, f0.w);
    p[2] = pk_bf16(f1.x, f1.y); p[3] = pk_bf16(f1.z, f1.w);
    p[4] = pk_bf16(f2.x, f2.y); p[5] = pk_bf16(f2.z, f2.w);
    p[6] = pk_bf16(f3.x, f3.y); p[7] = pk_bf16(f3.z, f3.w);
    *(uint4*)&As[arow * 32 + ach] = *(const uint4*)&p[0];
    *(uint4*)&As[arow * 32 + ach + 8] = *(const uint4*)&p[4];
    __syncthreads();
    bf16x8 af[4], bfr[4];
#pragma unroll
    for (int i = 0; i < 4; ++i)
      af[i] = *(const bf16x8*)&As[(wm * 64 + i * 16 + lr) * 32 + quad * 8];
#pragma unroll
    for (int j = 0; j < 4; ++j)
      bfr[j] = *(const bf16x8*)&Bs[(wn * 64 + j * 16 + lr) * 32 + quad * 8];
#pragma unroll
    for (int i = 0; i < 4; ++i)
#pragma unroll
      for (int j = 0; j < 4; ++j)
        acc[i][j] = __builtin_amdgcn_mfma_f32_16x16x32_bf16(af[i], bfr[j], acc[i][j], 0, 0, 0);
  }

#pragma unroll
  for (int i = 0; i < 4; ++i) {
    const int mg = m0 + wm * 64 + i * 16 + quad * 4;
#pragma unroll
    for (int j = 0; j < 4; ++j) {
      const int ng = n0 + wn * 64 + j * 16 + lr;
      const float bvv = bias[ng];
#pragma unroll
      for (int r = 0; r < 4; ++r)
        C[(size_t)(mg + r) * N + ng] = f2bf(acc[i][j][r] + bvv);
    }
  }
}

// Wvp[s][c] = Wv[h=c>>6][s][d=c&63], fp32 -> bf16. 8 outputs/thread (same h).
__global__ __launch_bounds__(256) void permute_wv(const float* __restrict__ Wv,
                                                  ushort_t* __restrict__ Wvp) {
  const int idx = (blockIdx.x * 256 + threadIdx.x) * 8;
  const int s = idx >> 9;
  const int c = idx & 511;
  const float* src = Wv + (size_t)(c >> 6) * (SD * DKK) + (size_t)s * DKK + (c & 63);
  float4 a = *(const float4*)src;
  float4 b = *(const float4*)(src + 4);
  unsigned int p[4];
  p[0] = pk_bf16(a.x, a.y); p[1] = pk_bf16(a.z, a.w);
  p[2] = pk_bf16(b.x, b.y); p[3] = pk_bf16(b.z, b.w);
  *(uint4*)(Wvp + idx) = *(const uint4*)p;
}

// Three weight transposes in one launch (z selects). dst[C][R] = src[R][C]^T.
__global__ __launch_bounds__(256) void transpose3(
    const float* __restrict__ s0, ushort_t* __restrict__ d0,
    const float* __restrict__ s1, ushort_t* __restrict__ d1,
    const float* __restrict__ s2, ushort_t* __restrict__ d2) {
  __shared__ ushort_t tile[32][33];
  const int z = blockIdx.z;
  const float* src = (z == 0) ? s0 : (z == 1) ? s1 : s2;
  ushort_t* dst = (z == 0) ? d0 : (z == 1) ? d1 : d2;
  const int R = (z == 2) ? 1024 : 512;
  const int C = (z == 1) ? 1024 : 512;
  const int bx = blockIdx.x * 32;  // col base in src
  const int by = blockIdx.y * 32;  // row base in src
  if (bx >= C || by >= R) return;
  const int tx = threadIdx.x, ty = threadIdx.y;
#pragma unroll
  for (int i = 0; i < 32; i += 8)
    tile[ty + i][tx] = f2bf(src[(size_t)(by + ty + i) * C + (bx + tx)]);
  __syncthreads();
#pragma unroll
  for (int i = 0; i < 32; i += 8)
    dst[(size_t)(bx + ty + i) * R + (by + tx)] = tile[tx][ty + i];
}

// c0[j] = sum_c bv[c]*Wo[c][j] + bo[j]. 16 blocks x 256 thr: 32 j's per
// block, 8-way split over c with LDS reduce (kills the latency-bound loop).
__global__ __launch_bounds__(256) void c0_kernel(const float* __restrict__ bv,
                                                 const float* __restrict__ Wo,
                                                 const float* __restrict__ bo,
                                                 float* __restrict__ c0) {
  __shared__ float red[8][32];
  const int jl = threadIdx.x & 31;
  const int chunk = threadIdx.x >> 5;  // 0..7
  const int j = blockIdx.x * 32 + jl;
  const int cbase = chunk * 64;
  float s = 0.f;
#pragma unroll 8
  for (int c = 0; c < 64; ++c) s += bv[cbase + c] * Wo[(size_t)(cbase + c) * 512 + j];
  red[chunk][jl] = s;
  __syncthreads();
  if (chunk == 0) {
    float t = bo[j];
#pragma unroll
    for (int q = 0; q < 8; ++q) t += red[q][jl];
    c0[j] = t;
  }
}

// out = LN(t + res) * g + b over rows of 512; one wave per row.
// t is bf16; res fp32 or bf16; out fp32 or bf16; g,b fp32.
template <int RES_F32, int OUT_F32>
__global__ __launch_bounds__(256) void ln_kernel(const ushort_t* __restrict__ t,
                                                 const void* __restrict__ res_,
                                                 const float* __restrict__ g,
                                                 const float* __restrict__ b,
                                                 void* __restrict__ out_) {
  const int row = blockIdx.x * 4 + (threadIdx.x >> 6);
  const int lane = threadIdx.x & 63;
  const size_t base = (size_t)row * 512 + lane * 8;
  uint4 tv = *(const uint4*)(t + base);
  const ushort_t* tp = (const ushort_t*)&tv;
  float r[8];
  if (RES_F32) {
    const float* res = (const float*)res_;
    float4 a = *(const float4*)(res + base);
    float4 c = *(const float4*)(res + base + 4);
    r[0] = a.x; r[1] = a.y; r[2] = a.z; r[3] = a.w;
    r[4] = c.x; r[5] = c.y; r[6] = c.z; r[7] = c.w;
  } else {
    const ushort_t* res = (const ushort_t*)res_;
    uint4 rv = *(const uint4*)(res + base);
    const ushort_t* rp = (const ushort_t*)&rv;
#pragma unroll
    for (int k = 0; k < 8; ++k) r[k] = bf2f(rp[k]);
  }
  float x[8];
  float s = 0.f, sq = 0.f;
#pragma unroll
  for (int k = 0; k < 8; ++k) {
    float v = bf2f(tp[k]) + r[k];
    x[k] = v; s += v; sq += v * v;
  }
#pragma unroll
  for (int off = 32; off > 0; off >>= 1) {
    s += __shfl_xor(s, off);
    sq += __shfl_xor(sq, off);
  }
  const float mean = s * (1.0f / 512.0f);
  const float var = sq * (1.0f / 512.0f) - mean * mean;
  const float rstd = rsqrtf(var + 1e-5f);
  float4 gv0 = *(const float4*)(g + lane * 8);
  float4 gv1 = *(const float4*)(g + lane * 8 + 4);
  float4 bv0 = *(const float4*)(b + lane * 8);
  float4 bv1 = *(const float4*)(b + lane * 8 + 4);
  const float gg[8] = {gv0.x, gv0.y, gv0.z, gv0.w, gv1.x, gv1.y, gv1.z, gv1.w};
  const float bb[8] = {bv0.x, bv0.y, bv0.z, bv0.w, bv1.x, bv1.y, bv1.z, bv1.w};
  float y[8];
#pragma unroll
  for (int k = 0; k < 8; ++k) y[k] = (x[k] - mean) * rstd * gg[k] + bb[k];
  if (OUT_F32) {
    float* out = (float*)out_;
    *(float4*)(out + base) = make_float4(y[0], y[1], y[2], y[3]);
    *(float4*)(out + base + 4) = make_float4(y[4], y[5], y[6], y[7]);
  } else {
    ushort_t* out = (ushort_t*)out_;
    uint4 ov; ushort_t* op = (ushort_t*)&ov;
#pragma unroll
    for (int k = 0; k < 8; ++k) op[k] = f2bf(y[k]);
    *(uint4*)(out + base) = ov;
  }
}

extern "C" void kernel_launch(void* const* d_in, const int* in_sizes, int n_in,
                              void* d_out, int out_size, void* d_ws, size_t ws_size,
                              hipStream_t stream) {
  const float* h_g  = (const float*)d_in[0];
  const float* h_s  = (const float*)d_in[1];
  // d_in[2..5] = Wq,bq,Wk,bk — dead code (softmax over 1 key == 1, attn == V)
  const float* Wv   = (const float*)d_in[6];
  const float* bv   = (const float*)d_in[7];
  const float* Wo   = (const float*)d_in[8];
  const float* bo   = (const float*)d_in[9];
  const float* ln1g = (const float*)d_in[10];
  const float* ln1b = (const float*)d_in[11];
  const float* W1   = (const float*)d_in[12];
  const float* b1   = (const float*)d_in[13];
  const float* W2   = (const float*)d_in[14];
  const float* b2   = (const float*)d_in[15];
  const float* ln2g = (const float*)d_in[16];
  const float* ln2b = (const float*)d_in[17];

  char* ws = (char*)d_ws;
  ushort_t* WoT = (ushort_t*)(ws + 0);           // 512x512 bf16   (0.5 MiB)
  ushort_t* W1T = (ushort_t*)(ws + 524288);      // 1024x512 bf16  (1 MiB)
  ushort_t* W2T = (ushort_t*)(ws + 1572864);     // 512x1024 bf16  (1 MiB)
  ushort_t* Wvp = (ushort_t*)(ws + 2621440);     // 3072x512 bf16  (3 MiB)
  ushort_t* WcT = (ushort_t*)(ws + 5767168);     // 512x3072 bf16  (3 MiB)
  float*    c0f = (float*)(ws + 8912896);        // 512 f32
  ushort_t* t1  = (ushort_t*)(ws + 9437184);     // 16384x512 bf16 (16 MiB)
  ushort_t* t2  = t1;                            // reuses t1 (dead after LN1)
  ushort_t* x   = (ushort_t*)(ws + 26214400);    // 16384x512 bf16 (16 MiB)
  ushort_t* u   = (ushort_t*)(ws + 42991616);    // 16384x1024 bf16 (32 MiB)
  (void)in_sizes; (void)n_in; (void)out_size; (void)ws_size;

  // --- prep ---
  hipLaunchKernelGGL(permute_wv, dim3(768), dim3(256), 0, stream, Wv, Wvp);
  hipLaunchKernelGGL(transpose3, dim3(32, 32, 3), dim3(32, 8), 0, stream,
                     Wo, WoT, W1, W1T, W2, W2T);
  hipLaunchKernelGGL(c0_kernel, dim3(16), dim3(256), 0, stream, bv, Wo, bo, c0f);

  // --- folded weight: WcT[j][s] = sum_c WoT[j][c] * Wvp[s][c]  (M=512,N=3072,K=512)
  hipLaunchKernelGGL(gemm_bt<0>, dim3(24, 4), dim3(256), 0, stream,
                     WoT, Wvp, WcT, (const float*)nullptr, 512, 3072, 512);
  // --- t1 = h_s @ Wc + c0   (M=16384,N=512,K=3072), A read directly as fp32
  hipLaunchKernelGGL(gemm_bt_f32a, dim3(4, 128), dim3(256), 0, stream,
                     h_s, WcT, t1, c0f, BB, 512, 3072);
  // --- x = LN1(t1 + h_g)   (res fp32, out bf16)
  hipLaunchKernelGGL((ln_kernel<1, 0>), dim3(4096), dim3(256), 0, stream,
                     t1, (const void*)h_g, ln1g, ln1b, (void*)x);
  // --- u = gelu(x @ W1 + b1)   (M=16384,N=1024,K=512)
  hipLaunchKernelGGL(gemm_bt<1>, dim3(8, 128), dim3(256), 0, stream,
                     x, W1T, u, b1, BB, 1024, 512);
  // --- t2 = u @ W2 + b2   (M=16384,N=512,K=1024)
  hipLaunchKernelGGL(gemm_bt<0>, dim3(4, 128), dim3(256), 0, stream,
                     u, W2T, t2, b2, BB, 512, 1024);
  // --- out = LN2(t2 + x)   (res bf16, out fp32)
  hipLaunchKernelGGL((ln_kernel<0, 1>), dim3(4096), dim3(256), 0, stream,
                     t2, (const void*)x, ln2g, ln2b, d_out);
}

// Round 4
// 550.192 us; speedup vs baseline: 1.0636x; 1.0437x over previous
//
#include <hip/hip_runtime.h>
#include <hip/hip_bf16.h>
#include <math.h>

// Dims from the reference
#define HH    8
#define DKK   64
#define GD    512
#define SD    3072
#define HID_  512
#define BB    16384

typedef unsigned short ushort_t;
typedef __attribute__((ext_vector_type(8))) short bf16x8;
typedef __attribute__((ext_vector_type(4))) float f32x4;

__device__ __forceinline__ float bf2f(ushort_t u) {
  union { unsigned int i; float f; } c; c.i = ((unsigned int)u) << 16; return c.f;
}
__device__ __forceinline__ ushort_t f2bf(float f) {
  union { float f; unsigned int i; } c; c.f = f;
  unsigned int x = c.i;
  return (ushort_t)((x + 0x7FFFu + ((x >> 16) & 1u)) >> 16);  // RNE
}
__device__ __forceinline__ unsigned int pk_bf16(float a, float b) {
  __hip_bfloat162 h = __float22bfloat162_rn(make_float2(a, b));
  union { __hip_bfloat162 h; unsigned int u; } c; c.h = h; return c.u;
}

__device__ __forceinline__ void async_cp16(const ushort_t* gsrc, ushort_t* ldst) {
  __builtin_amdgcn_global_load_lds(
      (const __attribute__((address_space(1))) unsigned int*)gsrc,
      (__attribute__((address_space(3))) unsigned int*)ldst, 16, 0, 0);
}
__device__ __forceinline__ void async_cp16f(const float* gsrc, float* ldst) {
  __builtin_amdgcn_global_load_lds(
      (const __attribute__((address_space(1))) unsigned int*)gsrc,
      (__attribute__((address_space(3))) unsigned int*)ldst, 16, 0, 0);
}

// tanh-form GELU: max |delta| vs exact erf-GELU ~3e-3, far under tolerance.
__device__ __forceinline__ float gelu_tanh(float x) {
  float y = 0.79788456080286535588f * (x + 0.044715f * x * x * x);
  float e = __expf(2.0f * y);
  float th = 1.0f - 2.0f / (e + 1.0f);
  return 0.5f * x * (1.0f + th);
}

// XCD-aware block swizzle: consecutive-bid blocks round-robin across 8 XCDs,
// so we map the NB N-siblings (which share an A row-tile) to bids differing
// by 8 -> same XCD -> A-tile fetched from HBM once per XCD, L2-served after.
// Requires NB, MB powers of two and NB*MB*KS % 8 == 0.
__device__ __forceinline__ void swz_coords(int& nb, int& mb, int& kz) {
  int NB = gridDim.x, MB = gridDim.y;
  int bid = blockIdx.x + NB * (blockIdx.y + MB * blockIdx.z);
  int xcd = bid & 7;
  int j = bid >> 3;
  nb = j & (NB - 1);
  int rest = j / NB;
  int mk = (rest << 3) | xcd;
  mb = mk & (MB - 1);
  kz = mk / MB;
}

// ---------------------------------------------------------------------------
// C[m][n] = sum_k A[m][k]*Bt[n][k] (+bias[n]); A,Bt bf16. BM=BN=128, BK=32.
// 4 waves, each a 64x64 subtile (4x4 of 16x16x32 MFMA), all-async staging.
// EPI: 0 = bias + bf16 store, 1 = gelu(bias+x) + bf16 store,
//      2 = raw fp32 partial store to C + kz*M*N (split-K; bias ignored).
// Split-K: grid.z = KS, each z covers Klen of Kfull.
// ---------------------------------------------------------------------------
template <int EPI, int SWZ>
__global__ __launch_bounds__(256) void gemm_bt(
    const ushort_t* __restrict__ A, const ushort_t* __restrict__ Bt,
    void* __restrict__ Cv, const float* __restrict__ bias,
    int M, int N, int Kfull, int Klen) {
  __shared__ __align__(16) ushort_t As[128 * 32];
  __shared__ __align__(16) ushort_t Bs[128 * 32];
  const int tid = threadIdx.x;
  const int wv = tid >> 6;
  const int lane = tid & 63;
  int nb, mb, kz;
  if (SWZ) swz_coords(nb, mb, kz);
  else { nb = blockIdx.x; mb = blockIdx.y; kz = blockIdx.z; }
  const int m0 = mb * 128, n0 = nb * 128, kbeg = kz * Klen;
  const int srow = lane >> 2;
  const int scol = (lane & 3) * 8;
  const int wm = wv & 1, wn = wv >> 1;
  const int lr = lane & 15, quad = lane >> 4;

  f32x4 acc[4][4];
#pragma unroll
  for (int i = 0; i < 4; ++i)
#pragma unroll
    for (int j = 0; j < 4; ++j) acc[i][j] = (f32x4){0.f, 0.f, 0.f, 0.f};

  const ushort_t* Ab = A + (size_t)m0 * Kfull + kbeg;
  const ushort_t* Bb = Bt + (size_t)n0 * Kfull + kbeg;

  for (int k0 = 0; k0 < Klen; k0 += 32) {
    __syncthreads();
#pragma unroll
    for (int i = 0; i < 2; ++i) {
      const int chunk = i * 4 + wv;          // wave-uniform
      const int row = chunk * 16 + srow;
      async_cp16(Ab + (size_t)row * Kfull + (k0 + scol), As + chunk * 512);
      async_cp16(Bb + (size_t)row * Kfull + (k0 + scol), Bs + chunk * 512);
    }
    __syncthreads();
    bf16x8 af[4], bfr[4];
#pragma unroll
    for (int i = 0; i < 4; ++i)
      af[i] = *(const bf16x8*)&As[(wm * 64 + i * 16 + lr) * 32 + quad * 8];
#pragma unroll
    for (int j = 0; j < 4; ++j)
      bfr[j] = *(const bf16x8*)&Bs[(wn * 64 + j * 16 + lr) * 32 + quad * 8];
#pragma unroll
    for (int i = 0; i < 4; ++i)
#pragma unroll
      for (int j = 0; j < 4; ++j)
        acc[i][j] = __builtin_amdgcn_mfma_f32_16x16x32_bf16(af[i], bfr[j], acc[i][j], 0, 0, 0);
  }

#pragma unroll
  for (int i = 0; i < 4; ++i) {
    const int mg = m0 + wm * 64 + i * 16 + quad * 4;
#pragma unroll
    for (int j = 0; j < 4; ++j) {
      const int ng = n0 + wn * 64 + j * 16 + lr;
      if (EPI == 2) {
        float* C = (float*)Cv + (size_t)kz * M * N;
#pragma unroll
        for (int r = 0; r < 4; ++r)
          C[(size_t)(mg + r) * N + ng] = acc[i][j][r];
      } else {
        ushort_t* C = (ushort_t*)Cv;
        const float bvv = bias ? bias[ng] : 0.0f;
#pragma unroll
        for (int r = 0; r < 4; ++r) {
          float v = acc[i][j][r] + bvv;
          if (EPI == 1) v = gelu_tanh(v);
          C[(size_t)(mg + r) * N + ng] = f2bf(v);
        }
      }
    }
  }
}

// ---------------------------------------------------------------------------
// Big GEMM: A fp32 in HBM, staged ASYNC into LDS as fp32 with an XOR-swizzled
// 16B-granule layout (slot g^(r&7)); fp32->bf16 conversion happens at
// fragment-read time. No ds_write (kills the 16-way write conflicts), no
// sync loads in the K-loop. Always split-K (EPI2-style fp32 partials) + XCD
// swizzle. BM=BN=128, BK=32; LDS = 16KB(A) + 8KB(B).
// ---------------------------------------------------------------------------
__global__ __launch_bounds__(256, 4) void gemm_a32(
    const float* __restrict__ A, const ushort_t* __restrict__ Bt,
    float* __restrict__ C, int M, int N, int Kfull, int Klen) {
  __shared__ __align__(16) float As4[128 * 32];     // 16 KB
  __shared__ __align__(16) ushort_t Bs[128 * 32];   // 8 KB
  const int tid = threadIdx.x;
  const int wv = tid >> 6;
  const int lane = tid & 63;
  int nb, mb, kz;
  swz_coords(nb, mb, kz);
  const int m0 = mb * 128, n0 = nb * 128, kbeg = kz * Klen;
  const int srow = lane >> 2;
  const int scol = (lane & 3) * 8;
  const int wm = wv & 1, wn = wv >> 1;
  const int lr = lane & 15, quad = lane >> 4;
  // A async staging mapping: instruction t covers chunk = t*4+wv (8 rows);
  // lane l -> row chunk*8 + (l>>3), fetches granule g = (l&7) ^ (l>>3).
  const int a_rc = lane >> 3;          // row within chunk
  const int a_g = (lane & 7) ^ a_rc;   // global 16B granule fetched

  f32x4 acc[4][4];
#pragma unroll
  for (int i = 0; i < 4; ++i)
#pragma unroll
    for (int j = 0; j < 4; ++j) acc[i][j] = (f32x4){0.f, 0.f, 0.f, 0.f};

  const float* Ab = A + (size_t)m0 * Kfull + kbeg;
  const ushort_t* Bb = Bt + (size_t)n0 * Kfull + kbeg;

  for (int k0 = 0; k0 < Klen; k0 += 32) {
    __syncthreads();
#pragma unroll
    for (int i = 0; i < 2; ++i) {
      const int chunk = i * 4 + wv;
      const int row = chunk * 16 + srow;
      async_cp16(Bb + (size_t)row * Kfull + (k0 + scol), Bs + chunk * 512);
    }
#pragma unroll
    for (int t = 0; t < 4; ++t) {
      const int chunkA = t * 4 + wv;             // wave-uniform, 0..15
      const int r = chunkA * 8 + a_rc;           // 0..127
      async_cp16f(Ab + (size_t)r * Kfull + (k0 + 4 * a_g), As4 + chunkA * 256);
    }
    __syncthreads();
    bf16x8 af[4], bfr[4];
#pragma unroll
    for (int i = 0; i < 4; ++i) {
      const int r = wm * 64 + i * 16 + lr;
      const int x0 = (2 * quad) ^ (lr & 7);
      const int x1 = (2 * quad + 1) ^ (lr & 7);
      float4 fa = *(const float4*)&As4[r * 32 + x0 * 4];
      float4 fb = *(const float4*)&As4[r * 32 + x1 * 4];
      union { unsigned int u[4]; bf16x8 v; } c;
      c.u[0] = pk_bf16(fa.x, fa.y); c.u[1] = pk_bf16(fa.z, fa.w);
      c.u[2] = pk_bf16(fb.x, fb.y); c.u[3] = pk_bf16(fb.z, fb.w);
      af[i] = c.v;
    }
#pragma unroll
    for (int j = 0; j < 4; ++j)
      bfr[j] = *(const bf16x8*)&Bs[(wn * 64 + j * 16 + lr) * 32 + quad * 8];
#pragma unroll
    for (int i = 0; i < 4; ++i)
#pragma unroll
      for (int j = 0; j < 4; ++j)
        acc[i][j] = __builtin_amdgcn_mfma_f32_16x16x32_bf16(af[i], bfr[j], acc[i][j], 0, 0, 0);
  }

  float* Cp = C + (size_t)kz * M * N;
#pragma unroll
  for (int i = 0; i < 4; ++i) {
    const int mg = m0 + wm * 64 + i * 16 + quad * 4;
#pragma unroll
    for (int j = 0; j < 4; ++j) {
      const int ng = n0 + wn * 64 + j * 16 + lr;
#pragma unroll
      for (int r = 0; r < 4; ++r)
        Cp[(size_t)(mg + r) * N + ng] = acc[i][j][r];
    }
  }
}

// Wvp[s][c] = Wv[h=c>>6][s][d=c&63], fp32 -> bf16. 8 outputs/thread (same h).
__global__ __launch_bounds__(256) void permute_wv(const float* __restrict__ Wv,
                                                  ushort_t* __restrict__ Wvp) {
  const int idx = (blockIdx.x * 256 + threadIdx.x) * 8;
  const int s = idx >> 9;
  const int c = idx & 511;
  const float* src = Wv + (size_t)(c >> 6) * (SD * DKK) + (size_t)s * DKK + (c & 63);
  float4 a = *(const float4*)src;
  float4 b = *(const float4*)(src + 4);
  unsigned int p[4];
  p[0] = pk_bf16(a.x, a.y); p[1] = pk_bf16(a.z, a.w);
  p[2] = pk_bf16(b.x, b.y); p[3] = pk_bf16(b.z, b.w);
  *(uint4*)(Wvp + idx) = *(const uint4*)p;
}

// Three weight transposes in one launch (z selects). dst[C][R] = src[R][C]^T.
__global__ __launch_bounds__(256) void transpose3(
    const float* __restrict__ s0, ushort_t* __restrict__ d0,
    const float* __restrict__ s1, ushort_t* __restrict__ d1,
    const float* __restrict__ s2, ushort_t* __restrict__ d2) {
  __shared__ ushort_t tile[32][33];
  const int z = blockIdx.z;
  const float* src = (z == 0) ? s0 : (z == 1) ? s1 : s2;
  ushort_t* dst = (z == 0) ? d0 : (z == 1) ? d1 : d2;
  const int R = (z == 2) ? 1024 : 512;
  const int C = (z == 1) ? 1024 : 512;
  const int bx = blockIdx.x * 32;
  const int by = blockIdx.y * 32;
  if (bx >= C || by >= R) return;
  const int tx = threadIdx.x, ty = threadIdx.y;
#pragma unroll
  for (int i = 0; i < 32; i += 8)
    tile[ty + i][tx] = f2bf(src[(size_t)(by + ty + i) * C + (bx + tx)]);
  __syncthreads();
#pragma unroll
  for (int i = 0; i < 32; i += 8)
    dst[(size_t)(bx + ty + i) * R + (by + tx)] = tile[tx][ty + i];
}

// c0[j] = sum_c bv[c]*Wo[c][j] + bo[j].
__global__ __launch_bounds__(256) void c0_kernel(const float* __restrict__ bv,
                                                 const float* __restrict__ Wo,
                                                 const float* __restrict__ bo,
                                                 float* __restrict__ c0) {
  __shared__ float red[8][32];
  const int jl = threadIdx.x & 31;
  const int chunk = threadIdx.x >> 5;
  const int j = blockIdx.x * 32 + jl;
  const int cbase = chunk * 64;
  float s = 0.f;
#pragma unroll 8
  for (int c = 0; c < 64; ++c) s += bv[cbase + c] * Wo[(size_t)(cbase + c) * 512 + j];
  red[chunk][jl] = s;
  __syncthreads();
  if (chunk == 0) {
    float t = bo[j];
#pragma unroll
    for (int q = 0; q < 8; ++q) t += red[q][jl];
    c0[j] = t;
  }
}

// out = LN(p0 + p1 + cb + res) * g + b over rows of 512; one wave per row.
// p0,p1 fp32 split-K partials; cb fp32 column bias; res fp32 or bf16.
template <int RES_F32, int OUT_F32>
__global__ __launch_bounds__(256) void ln_fused(const float* __restrict__ p0,
                                                const float* __restrict__ p1,
                                                const float* __restrict__ cb,
                                                const void* __restrict__ res_,
                                                const float* __restrict__ g,
                                                const float* __restrict__ b,
                                                void* __restrict__ out_) {
  const int row = blockIdx.x * 4 + (threadIdx.x >> 6);
  const int lane = threadIdx.x & 63;
  const size_t base = (size_t)row * 512 + lane * 8;
  const int col = lane * 8;
  float4 a0 = *(const float4*)(p0 + base);
  float4 a1 = *(const float4*)(p0 + base + 4);
  float4 c0v = *(const float4*)(p1 + base);
  float4 c1v = *(const float4*)(p1 + base + 4);
  float4 d0 = *(const float4*)(cb + col);
  float4 d1 = *(const float4*)(cb + col + 4);
  float t[8];
  t[0] = a0.x + c0v.x + d0.x; t[1] = a0.y + c0v.y + d0.y;
  t[2] = a0.z + c0v.z + d0.z; t[3] = a0.w + c0v.w + d0.w;
  t[4] = a1.x + c1v.x + d1.x; t[5] = a1.y + c1v.y + d1.y;
  t[6] = a1.z + c1v.z + d1.z; t[7] = a1.w + c1v.w + d1.w;
  float r[8];
  if (RES_F32) {
    const float* res = (const float*)res_;
    float4 e0 = *(const float4*)(res + base);
    float4 e1 = *(const float4*)(res + base + 4);
    r[0] = e0.x; r[1] = e0.y; r[2] = e0.z; r[3] = e0.w;
    r[4] = e1.x; r[5] = e1.y; r[6] = e1.z; r[7] = e1.w;
  } else {
    const ushort_t* res = (const ushort_t*)res_;
    uint4 rv = *(const uint4*)(res + base);
    const ushort_t* rp = (const ushort_t*)&rv;
#pragma unroll
    for (int k = 0; k < 8; ++k) r[k] = bf2f(rp[k]);
  }
  float x[8];
  float s = 0.f, sq = 0.f;
#pragma unroll
  for (int k = 0; k < 8; ++k) {
    float v = t[k] + r[k];
    x[k] = v; s += v; sq += v * v;
  }
#pragma unroll
  for (int off = 32; off > 0; off >>= 1) {
    s += __shfl_xor(s, off);
    sq += __shfl_xor(sq, off);
  }
  const float mean = s * (1.0f / 512.0f);
  const float var = sq * (1.0f / 512.0f) - mean * mean;
  const float rstd = rsqrtf(var + 1e-5f);
  float4 gv0 = *(const float4*)(g + col);
  float4 gv1 = *(const float4*)(g + col + 4);
  float4 bv0 = *(const float4*)(b + col);
  float4 bv1 = *(const float4*)(b + col + 4);
  const float gg[8] = {gv0.x, gv0.y, gv0.z, gv0.w, gv1.x, gv1.y, gv1.z, gv1.w};
  const float bb[8] = {bv0.x, bv0.y, bv0.z, bv0.w, bv1.x, bv1.y, bv1.z, bv1.w};
  float y[8];
#pragma unroll
  for (int k = 0; k < 8; ++k) y[k] = (x[k] - mean) * rstd * gg[k] + bb[k];
  if (OUT_F32) {
    float* out = (float*)out_;
    *(float4*)(out + base) = make_float4(y[0], y[1], y[2], y[3]);
    *(float4*)(out + base + 4) = make_float4(y[4], y[5], y[6], y[7]);
  } else {
    ushort_t* out = (ushort_t*)out_;
    uint4 ov; ushort_t* op = (ushort_t*)&ov;
#pragma unroll
    for (int k = 0; k < 8; ++k) op[k] = f2bf(y[k]);
    *(uint4*)(out + base) = ov;
  }
}

extern "C" void kernel_launch(void* const* d_in, const int* in_sizes, int n_in,
                              void* d_out, int out_size, void* d_ws, size_t ws_size,
                              hipStream_t stream) {
  const float* h_g  = (const float*)d_in[0];
  const float* h_s  = (const float*)d_in[1];
  // d_in[2..5] = Wq,bq,Wk,bk — dead code (softmax over 1 key == 1, attn == V)
  const float* Wv   = (const float*)d_in[6];
  const float* bv   = (const float*)d_in[7];
  const float* Wo   = (const float*)d_in[8];
  const float* bo   = (const float*)d_in[9];
  const float* ln1g = (const float*)d_in[10];
  const float* ln1b = (const float*)d_in[11];
  const float* W1   = (const float*)d_in[12];
  const float* b1   = (const float*)d_in[13];
  const float* W2   = (const float*)d_in[14];
  const float* b2   = (const float*)d_in[15];
  const float* ln2g = (const float*)d_in[16];
  const float* ln2b = (const float*)d_in[17];

  char* ws = (char*)d_ws;
  ushort_t* WoT = (ushort_t*)(ws + 0);            // 512x512 bf16   (0.5 MiB)
  ushort_t* W1T = (ushort_t*)(ws + 524288);       // 1024x512 bf16  (1 MiB)
  ushort_t* W2T = (ushort_t*)(ws + 1572864);      // 512x1024 bf16  (1 MiB)
  ushort_t* Wvp = (ushort_t*)(ws + 2621440);      // 3072x512 bf16  (3 MiB)
  ushort_t* WcT = (ushort_t*)(ws + 5767168);      // 512x3072 bf16  (3 MiB)
  float*    c0f = (float*)(ws + 8912896);         // 512 f32
  float*    p0  = (float*)(ws + 16777216);        // 16384x512 f32  (32 MiB)
  float*    p1  = (float*)(ws + 50331648);        // 16384x512 f32  (32 MiB)
  ushort_t* x   = (ushort_t*)(ws + 83886080);     // 16384x512 bf16 (16 MiB)
  ushort_t* u   = (ushort_t*)(ws + 100663296);    // 16384x1024 bf16 (32 MiB)
  // q0/q1 (W2 partials) alias p0/p1 — p* are dead after LN1.
  float*    q0  = p0;
  float*    q1  = p1;
  (void)in_sizes; (void)n_in; (void)out_size; (void)ws_size;

  // --- prep (tiny) ---
  hipLaunchKernelGGL(permute_wv, dim3(768), dim3(256), 0, stream, Wv, Wvp);
  hipLaunchKernelGGL(transpose3, dim3(32, 32, 3), dim3(32, 8), 0, stream,
                     Wo, WoT, W1, W1T, W2, W2T);
  hipLaunchKernelGGL(c0_kernel, dim3(16), dim3(256), 0, stream, bv, Wo, bo, c0f);

  // --- folded weight: WcT[j][s] = sum_c WoT[j][c] * Wvp[s][c]  (M=512,N=3072,K=512)
  hipLaunchKernelGGL((gemm_bt<0, 0>), dim3(24, 4, 1), dim3(256), 0, stream,
                     WoT, Wvp, (void*)WcT, (const float*)nullptr, 512, 3072, 512, 512);
  // --- p0,p1 = split-K partials of h_s @ Wc   (M=16384,N=512,K=3072, ks=2)
  hipLaunchKernelGGL(gemm_a32, dim3(4, 128, 2), dim3(256), 0, stream,
                     h_s, WcT, p0, BB, 512, 3072, 1536);
  // --- x = LN1(p0 + p1 + c0 + h_g)   (res fp32, out bf16)
  hipLaunchKernelGGL((ln_fused<1, 0>), dim3(4096), dim3(256), 0, stream,
                     p0, p1, c0f, (const void*)h_g, ln1g, ln1b, (void*)x);
  // --- u = gelu(x @ W1 + b1)   (M=16384,N=1024,K=512)
  hipLaunchKernelGGL((gemm_bt<1, 1>), dim3(8, 128, 1), dim3(256), 0, stream,
                     x, W1T, (void*)u, b1, BB, 1024, 512, 512);
  // --- q0,q1 = split-K partials of u @ W2   (M=16384,N=512,K=1024, ks=2)
  hipLaunchKernelGGL((gemm_bt<2, 1>), dim3(4, 128, 2), dim3(256), 0, stream,
                     u, W2T, (void*)q0, (const float*)nullptr, BB, 512, 1024, 512);
  // --- out = LN2(q0 + q1 + b2 + x)   (res bf16, out fp32)
  hipLaunchKernelGGL((ln_fused<0, 1>), dim3(4096), dim3(256), 0, stream,
                     q0, q1, b2, (const void*)x, ln2g, ln2b, d_out);
}